// Round 11
// baseline (173.856 us; speedup 1.0000x reference)
//
#include <hip/hip_runtime.h>
#include <stdint.h>

// ---------------------------------------------------------------------------
// MultiHeadPointAttention (B=2, N=8192, K=16, H=4, Cin=64, Cout=128, D=32)
//
//   prep_frags    : weights -> bf16 MFMA B-fragment layout in ws
//   qkv_kernel    : q(f32),k,v(bf16) = x @ [Wq|Wkv] + bias; per-block LDS B-slice
//   fused_attn_wo : block=512 (8 waves), NPW=1, 52 KB LDS -> 3 blocks/CU.
//                   32 KB sB cycled Wp2->Wa1->Wa2, 6 barriers. t-pair GEMM
//                   loops with fused epilogues (acc live = 8 regs). ba2
//                   dropped (cancels in softmax). All gathers prefetched;
//                   v is packed into a flat uint32_t[16] AT LOAD TIME.
//
// R10 lesson: ushort[8][4] held across the restage defeated SROA -> lowered
// to scratch (WRITE_SIZE 8->53 MB with 30 regs spare). Word-sized flat
// constant-indexed arrays promote; sub-word 2-D arrays don't.
//
// MFMA 16x16x32 bf16 layouts (HW-verified):
//   A[m][k]: m = lane&15, k = (lane>>4)*8 + j
//   B[k][n]: n = lane&15, k = (lane>>4)*8 + j
//   D[r][c]: c = lane&15, r = (lane>>4)*4 + reg
// ---------------------------------------------------------------------------

typedef __attribute__((ext_vector_type(8))) short short8;
typedef __attribute__((ext_vector_type(4))) float f32x4;
typedef __attribute__((ext_vector_type(4))) unsigned int u32x4;

#define NN_TOT 16384   // B*N
#define SLW 72         // slab row stride in shorts (64 cols + 8 pad)

__device__ __forceinline__ uint32_t pk_bf16(float a, float b) {
  uint32_t r;
  asm("v_cvt_pk_bf16_f32 %0, %1, %2" : "=v"(r) : "v"(a), "v"(b));
  return r;  // low = bf16(a), high = bf16(b)
}
__device__ __forceinline__ float lo_f(uint32_t p) {
  return __builtin_bit_cast(float, p << 16);
}
__device__ __forceinline__ float hi_f(uint32_t p) {
  return __builtin_bit_cast(float, p & 0xffff0000u);
}
__device__ __forceinline__ short f2bf_rne(float f) {   // prep only
  uint32_t u = __builtin_bit_cast(uint32_t, f);
  uint32_t r = (u + 0x7FFFu + ((u >> 16) & 1u)) >> 16;
  return (short)r;
}
__device__ __forceinline__ float bf2f(unsigned short s) {
  uint32_t u = ((uint32_t)s) << 16;
  return __builtin_bit_cast(float, u);
}

__global__ __launch_bounds__(256) void prep_frags(
    const float* __restrict__ Wq, const float* __restrict__ Wkv,
    const float* __restrict__ Wp2, const float* __restrict__ Wa1,
    const float* __restrict__ Wa2, const float* __restrict__ Wo,
    short* __restrict__ fqh, short* __restrict__ fql,
    short* __restrict__ fwp2, short* __restrict__ fwa1, short* __restrict__ fwa2,
    short* __restrict__ fwoh, short* __restrict__ fwol) {
  int r = blockIdx.x * 256 + threadIdx.x;   // grid = 44*256 = 11264 exact
  if (r < 3072) {
    int t = r >> 7, rem = r & 127, s = rem >> 6, lane = rem & 63;
    int quad = lane >> 4, l15 = lane & 15;
    int col = t * 16 + l15;
    #pragma unroll
    for (int j = 0; j < 8; j++) {
      int i = 32 * s + quad * 8 + j;
      float wv = (col < 128) ? Wq[i * 128 + col] : Wkv[i * 256 + (col - 128)];
      short hi = f2bf_rne(wv);
      fqh[r * 8 + j] = hi;
      fql[r * 8 + j] = f2bf_rne(wv - bf2f((unsigned short)hi));
    }
  } else {
    int r2 = r - 3072;
    int mat = r2 >> 11;        // 0:Wp2 1:Wa1 2:Wa2 3:Wo
    int rr = r2 & 2047;
    int t = rr >> 8, rem = rr & 255, s = rem >> 6, lane = rem & 63;
    int quad = lane >> 4, l15 = lane & 15;
    int col = t * 16 + l15;
    const float* W = (mat == 0) ? Wp2 : (mat == 1) ? Wa1 : (mat == 2) ? Wa2 : Wo;
    #pragma unroll
    for (int j = 0; j < 8; j++) {
      int i = 32 * s + quad * 8 + j;
      float wv = W[i * 128 + col];
      short hi = f2bf_rne(wv);
      if (mat == 3) {
        fwoh[rr * 8 + j] = hi;
        fwol[rr * 8 + j] = f2bf_rne(wv - bf2f((unsigned short)hi));
      } else if (mat == 0) fwp2[rr * 8 + j] = hi;
      else if (mat == 1)   fwa1[rr * 8 + j] = hi;
      else                 fwa2[rr * 8 + j] = hi;
    }
  }
}

__device__ __forceinline__ void split_frag(const f32x4 x0, const f32x4 x1,
                                           short8& ah, short8& al) {
  uint32_t h01 = pk_bf16(x0[0], x0[1]);
  uint32_t h23 = pk_bf16(x0[2], x0[3]);
  uint32_t h45 = pk_bf16(x1[0], x1[1]);
  uint32_t h67 = pk_bf16(x1[2], x1[3]);
  u32x4 hh = {h01, h23, h45, h67};
  ah = __builtin_bit_cast(short8, hh);
  uint32_t l01 = pk_bf16(x0[0] - lo_f(h01), x0[1] - hi_f(h01));
  uint32_t l23 = pk_bf16(x0[2] - lo_f(h23), x0[3] - hi_f(h23));
  uint32_t l45 = pk_bf16(x1[0] - lo_f(h45), x1[1] - hi_f(h45));
  uint32_t l67 = pk_bf16(x1[2] - lo_f(h67), x1[3] - hi_f(h67));
  u32x4 ll = {l01, l23, l45, l67};
  al = __builtin_bit_cast(short8, ll);
}

// ---------------------------------------------------------------------------
// q,k,v projection. Block = 256 thr (4 waves), one section per block
// (0=q f32, 1=k bf16, 2=v bf16); section B-slice (32 KB hi+lo) in LDS.
// ---------------------------------------------------------------------------
__global__ __launch_bounds__(256) void qkv_kernel(
    const float* __restrict__ x, const float* __restrict__ bq,
    const float* __restrict__ bkv,
    const short* __restrict__ fqh, const short* __restrict__ fql,
    float* __restrict__ q, unsigned short* __restrict__ ko,
    unsigned short* __restrict__ vo) {
  __shared__ __align__(16) short sBq[16384];   // hi [0..8191], lo [8192..16383]
  const int tid = threadIdx.x;
  const int sec = blockIdx.x >> 8;             // 0..2
  const int gq = blockIdx.x & 255;
  const int w = tid >> 6, lane = tid & 63;
  const int quad = lane >> 4, l15 = lane & 15;

  {  // stage 16 KB hi + 16 KB lo of this section's frag rows
    const u32x4* sh = reinterpret_cast<const u32x4*>(fqh + sec * 8192);
    const u32x4* sl = reinterpret_cast<const u32x4*>(fql + sec * 8192);
    u32x4* dh = reinterpret_cast<u32x4*>(sBq);
    u32x4* dl = reinterpret_cast<u32x4*>(sBq + 8192);
    #pragma unroll
    for (int i = 0; i < 4; i++) {
      dh[tid + i * 256] = sh[tid + i * 256];
      dl[tid + i * 256] = sl[tid + i * 256];
    }
  }

  const int base = (gq * 4 + w) * 16;
  short8 ah[2], al[2];
  #pragma unroll
  for (int s = 0; s < 2; s++) {
    const float* xp = x + (base + l15) * 64 + 32 * s + quad * 8;
    split_frag(*reinterpret_cast<const f32x4*>(xp),
               *reinterpret_cast<const f32x4*>(xp + 4), ah[s], al[s]);
  }
  __syncthreads();

  #pragma unroll
  for (int tt = 0; tt < 8; tt++) {
    f32x4 acc = {0.f, 0.f, 0.f, 0.f};
    #pragma unroll
    for (int s = 0; s < 2; s++) {
      int rt = tt * 2 + s;
      short8 bh = *reinterpret_cast<const short8*>(sBq + rt * 512 + lane * 8);
      short8 bl = *reinterpret_cast<const short8*>(sBq + 8192 + rt * 512 + lane * 8);
      acc = __builtin_amdgcn_mfma_f32_16x16x32_bf16(ah[s], bh, acc, 0, 0, 0);
      acc = __builtin_amdgcn_mfma_f32_16x16x32_bf16(ah[s], bl, acc, 0, 0, 0);
      acc = __builtin_amdgcn_mfma_f32_16x16x32_bf16(al[s], bh, acc, 0, 0, 0);
    }
    int cl = tt * 16 + l15;                       // column within section
    if (sec == 0) {
      float bias = bq[cl];
      #pragma unroll
      for (int r = 0; r < 4; r++)
        q[(base + quad * 4 + r) * 128 + cl] = acc[r] + bias;
    } else {
      float bias = bkv[(sec - 1) * 128 + cl];
      unsigned short* dst = (sec == 1) ? ko : vo;
      #pragma unroll
      for (int r = 0; r < 4; r++) {
        float vv = acc[r] + bias;
        dst[(base + quad * 4 + r) * 128 + cl] = (unsigned short)pk_bf16(vv, vv);
      }
    }
  }
}

// ---------------------------------------------------------------------------
// Fused attention + Wo. Block = 512 thr (8 waves), 8 nodes (1/wave), 52 KB
// LDS -> 3 blocks/CU. sB (32 KB) cycled Wp2 / Wa1 / Wa2. t-pair fused
// epilogues; k,q,v all prefetched (v packed at load into uint32[16]).
// ---------------------------------------------------------------------------
__global__ __launch_bounds__(512, 6) void fused_attn_wo(
    const float* __restrict__ pos, const int* __restrict__ idx,
    const float* __restrict__ Wp1, const float* __restrict__ bp1,
    const float* __restrict__ bp2, const float* __restrict__ ba1,
    const short* __restrict__ fwp2, const short* __restrict__ fwa1,
    const short* __restrict__ fwa2,
    const short* __restrict__ fwoh, const short* __restrict__ fwol,
    const float* __restrict__ bo,
    const float* __restrict__ qg, const unsigned short* __restrict__ kg,
    const unsigned short* __restrict__ vg, float* __restrict__ out) {
  __shared__ __align__(16) short sB[16384];                   // 32 KB, cycled
  __shared__ __align__(16) unsigned short slab[8][16 * SLW];  // 18 KB half-width
  __shared__ float spd[8][16][3];
  __shared__ int sidx[8][16];
  // sagg overlays slab (8 rows x 132 f32 = 4224 B). All slab reads complete
  // before barrier 5; sagg writes follow (every wave passes barrier 5 first).
  float (*sagg)[132] = reinterpret_cast<float(*)[132]>(&slab[0][0]);

  const int tid = threadIdx.x;
  const int w = tid >> 6;
  const int lane = tid & 63;
  const int quad = lane >> 4, l15 = lane & 15;
  const int nb0 = blockIdx.x * 8;
  const int node = nb0 + w;
  unsigned short* myslab = &slab[w][0];

  // ---- neighbor idx + pos_diff (wave-private) ----
  if (lane < 16) {
    int ji = idx[node * 16 + lane];
    int jn = ((node >> 13) << 13) + ji;
    sidx[w][lane] = jn;
    spd[w][lane][0] = pos[node * 3 + 0] - pos[jn * 3 + 0];
    spd[w][lane][1] = pos[node * 3 + 1] - pos[jn * 3 + 1];
    spd[w][lane][2] = pos[node * 3 + 2] - pos[jn * 3 + 2];
  }

  // ---- stage sB <- Wp2 frags (32 KB, all threads) ----
  {
    const u32x4* s4 = reinterpret_cast<const u32x4*>(fwp2);
    u32x4* d4 = reinterpret_cast<u32x4*>(sB);
    #pragma unroll
    for (int i = 0; i < 4; i++) d4[tid + i * 512] = s4[tid + i * 512];
  }

  // ---- pos MLP layer 1 -> slab (two column-phases) -> aP frags ----
  short8 aP[4];
  #pragma unroll
  for (int p = 0; p < 2; p++) {
    const int c = lane + p * 64;           // channel; slab col = lane
    float wp0 = Wp1[c], wp1 = Wp1[128 + c], wp2v = Wp1[256 + c], bb = bp1[c];
    #pragma unroll
    for (int m = 0; m < 16; m++) {
      float h = fmaxf(bb + spd[w][m][0] * wp0 + spd[w][m][1] * wp1 +
                           spd[w][m][2] * wp2v, 0.f);
      myslab[m * SLW + lane] = (unsigned short)pk_bf16(h, h);
    }
    #pragma unroll
    for (int ss = 0; ss < 2; ss++)
      aP[p * 2 + ss] = *reinterpret_cast<const short8*>(
          myslab + l15 * SLW + 32 * ss + quad * 8);
  }
  __syncthreads();   // barrier 1: sB = Wp2 ready

  // ---- gathers: k (packed bf16) + q in C/D layout (hide under GEMM1) ----
  short8 k_pk[4];
  float qv[8];
  int vb[4];
  {
    const unsigned short* kp = kg + sidx[w][l15] * 128;
    #pragma unroll
    for (int s = 0; s < 4; s++)
      k_pk[s] = *reinterpret_cast<const short8*>(kp + 32 * s + quad * 8);
    const float* qrow = qg + node * 128;
    #pragma unroll
    for (int t = 0; t < 8; t++) qv[t] = qrow[16 * t + l15];
    #pragma unroll
    for (int r = 0; r < 4; r++) vb[r] = sidx[w][quad * 4 + r] * 128;
  }

  uint32_t pe_pk[8][2];
  short8 a2[4];

  // ---- GEMM1 (t-pairs, fused pe epilogue): pos_enc = pos_hidden @ Wp2 ----
  #pragma unroll
  for (int p = 0; p < 2; p++) {
    #pragma unroll
    for (int half = 0; half < 2; half++) {
      const int t0 = p * 4 + half * 2, t1 = t0 + 1;
      f32x4 aa = {0.f, 0.f, 0.f, 0.f}, ab = {0.f, 0.f, 0.f, 0.f};
      #pragma unroll
      for (int s = 0; s < 4; s++) {
        short8 b0 = *reinterpret_cast<const short8*>(sB + ((t0 * 4 + s) * 64 + lane) * 8);
        short8 b1 = *reinterpret_cast<const short8*>(sB + ((t1 * 4 + s) * 64 + lane) * 8);
        aa = __builtin_amdgcn_mfma_f32_16x16x32_bf16(aP[s], b0, aa, 0, 0, 0);
        ab = __builtin_amdgcn_mfma_f32_16x16x32_bf16(aP[s], b1, ab, 0, 0, 0);
      }
      #pragma unroll
      for (int e = 0; e < 2; e++) {
        const int t = e ? t1 : t0;
        const f32x4 ac = e ? ab : aa;
        float bb = bp2[16 * t + l15];
        float f0 = ac[0] + bb, f1 = ac[1] + bb, f2 = ac[2] + bb, f3 = ac[3] + bb;
        pe_pk[t][0] = pk_bf16(f0, f1);
        pe_pk[t][1] = pk_bf16(f2, f3);
        float q_ = qv[t];
        uint32_t g01 = pk_bf16(f0 - q_, f1 - q_);
        uint32_t g23 = pk_bf16(f2 - q_, f3 - q_);
        int cl = 16 * (t & 3) + l15;
        myslab[(quad * 4 + 0) * SLW + cl] = (unsigned short)g01;
        myslab[(quad * 4 + 1) * SLW + cl] = (unsigned short)(g01 >> 16);
        myslab[(quad * 4 + 2) * SLW + cl] = (unsigned short)g23;
        myslab[(quad * 4 + 3) * SLW + cl] = (unsigned short)(g23 >> 16);
      }
    }
    // build a2 for this phase: rel = k + (pe - q)
    #pragma unroll
    for (int ss = 0; ss < 2; ss++) {
      int s = p * 2 + ss;
      short8 pq = *reinterpret_cast<const short8*>(
          myslab + l15 * SLW + 32 * ss + quad * 8);
      short8 kk = k_pk[s];
      u32x4 av = {pk_bf16(bf2f((unsigned short)kk[0]) + bf2f((unsigned short)pq[0]),
                          bf2f((unsigned short)kk[1]) + bf2f((unsigned short)pq[1])),
                  pk_bf16(bf2f((unsigned short)kk[2]) + bf2f((unsigned short)pq[2]),
                          bf2f((unsigned short)kk[3]) + bf2f((unsigned short)pq[3])),
                  pk_bf16(bf2f((unsigned short)kk[4]) + bf2f((unsigned short)pq[4]),
                          bf2f((unsigned short)kk[5]) + bf2f((unsigned short)pq[5])),
                  pk_bf16(bf2f((unsigned short)kk[6]) + bf2f((unsigned short)pq[6]),
                          bf2f((unsigned short)kk[7]) + bf2f((unsigned short)pq[7]))};
      a2[s] = __builtin_bit_cast(short8, av);
    }
  }
  __syncthreads();   // barrier 2: all waves done reading Wp2

  // ---- restage sB <- Wa1 ----
  {
    const u32x4* s4 = reinterpret_cast<const u32x4*>(fwa1);
    u32x4* d4 = reinterpret_cast<u32x4*>(sB);
    #pragma unroll
    for (int i = 0; i < 4; i++) d4[tid + i * 512] = s4[tid + i * 512];
  }
  __syncthreads();   // barrier 3: sB = Wa1 ready

  // ---- GEMM2 (t-pairs, fused relu epilogue): hidden = relu(rel@Wa1+ba1) ----
  short8 a3[4];
  #pragma unroll
  for (int p = 0; p < 2; p++) {
    #pragma unroll
    for (int half = 0; half < 2; half++) {
      const int t0 = p * 4 + half * 2, t1 = t0 + 1;
      f32x4 aa = {0.f, 0.f, 0.f, 0.f}, ab = {0.f, 0.f, 0.f, 0.f};
      #pragma unroll
      for (int s = 0; s < 4; s++) {
        short8 b0 = *reinterpret_cast<const short8*>(sB + ((t0 * 4 + s) * 64 + lane) * 8);
        short8 b1 = *reinterpret_cast<const short8*>(sB + ((t1 * 4 + s) * 64 + lane) * 8);
        aa = __builtin_amdgcn_mfma_f32_16x16x32_bf16(a2[s], b0, aa, 0, 0, 0);
        ab = __builtin_amdgcn_mfma_f32_16x16x32_bf16(a2[s], b1, ab, 0, 0, 0);
      }
      #pragma unroll
      for (int e = 0; e < 2; e++) {
        const int t = e ? t1 : t0;
        const f32x4 ac = e ? ab : aa;
        float bb = ba1[16 * t + l15];
        uint32_t p01 = pk_bf16(fmaxf(ac[0] + bb, 0.f), fmaxf(ac[1] + bb, 0.f));
        uint32_t p23 = pk_bf16(fmaxf(ac[2] + bb, 0.f), fmaxf(ac[3] + bb, 0.f));
        int cl = 16 * (t & 3) + l15;
        myslab[(quad * 4 + 0) * SLW + cl] = (unsigned short)p01;
        myslab[(quad * 4 + 1) * SLW + cl] = (unsigned short)(p01 >> 16);
        myslab[(quad * 4 + 2) * SLW + cl] = (unsigned short)p23;
        myslab[(quad * 4 + 3) * SLW + cl] = (unsigned short)(p23 >> 16);
      }
    }
    #pragma unroll
    for (int ss = 0; ss < 2; ss++)
      a3[p * 2 + ss] = *reinterpret_cast<const short8*>(
          myslab + l15 * SLW + 32 * ss + quad * 8);
  }
  __syncthreads();   // barrier 4: all waves done reading Wa1

  // ---- v prefetch: 32 bf16 loads packed AT LOAD into flat uint32[16]
  //      (word-sized, constant-indexed -> SROA promotes; R10's ushort[8][4]
  //      went to scratch). Hidden behind Wa2 restage + barrier + GEMM3. ----
  uint32_t vp[16];
  #pragma unroll
  for (int t = 0; t < 8; t++) {
    int c = 16 * t + l15;
    uint32_t a0 = vg[vb[0] + c];
    uint32_t a1 = vg[vb[1] + c];
    uint32_t a2v = vg[vb[2] + c];
    uint32_t a3v = vg[vb[3] + c];
    vp[2 * t]     = a0 | (a1 << 16);
    vp[2 * t + 1] = a2v | (a3v << 16);
  }

  // ---- restage sB <- Wa2 ----
  {
    const u32x4* s4 = reinterpret_cast<const u32x4*>(fwa2);
    u32x4* d4 = reinterpret_cast<u32x4*>(sB);
    #pragma unroll
    for (int i = 0; i < 4; i++) d4[tid + i * 512] = s4[tid + i * 512];
  }
  __syncthreads();   // barrier 5: sB = Wa2 ready; all slab reads done

  // ---- GEMM3 (t-pairs, fused softmax+agg epilogue). ba2 cancels. ----
  #pragma unroll
  for (int tp = 0; tp < 4; tp++) {
    const int t0 = tp * 2, t1 = t0 + 1;
    f32x4 aa = {0.f, 0.f, 0.f, 0.f}, ab = {0.f, 0.f, 0.f, 0.f};
    #pragma unroll
    for (int s = 0; s < 4; s++) {
      short8 b0 = *reinterpret_cast<const short8*>(sB + ((t0 * 4 + s) * 64 + lane) * 8);
      short8 b1 = *reinterpret_cast<const short8*>(sB + ((t1 * 4 + s) * 64 + lane) * 8);
      aa = __builtin_amdgcn_mfma_f32_16x16x32_bf16(a3[s], b0, aa, 0, 0, 0);
      ab = __builtin_amdgcn_mfma_f32_16x16x32_bf16(a3[s], b1, ab, 0, 0, 0);
    }
    #pragma unroll
    for (int e = 0; e < 2; e++) {
      const int t = e ? t1 : t0;
      const f32x4 ac = e ? ab : aa;
      int c = 16 * t + l15;
      float g0 = ac[0], g1 = ac[1], g2 = ac[2], g3 = ac[3];
      float mx = fmaxf(fmaxf(g0, g1), fmaxf(g2, g3));
      mx = fmaxf(mx, __shfl_xor(mx, 16));
      mx = fmaxf(mx, __shfl_xor(mx, 32));
      float e0 = __expf(g0 - mx), e1 = __expf(g1 - mx);
      float e2 = __expf(g2 - mx), e3 = __expf(g3 - mx);
      float ls = e0 + e1 + e2 + e3;
      ls += __shfl_xor(ls, 16);
      ls += __shfl_xor(ls, 32);
      float pe0 = lo_f(pe_pk[t][0]), pe1 = hi_f(pe_pk[t][0]);
      float pe2 = lo_f(pe_pk[t][1]), pe3 = hi_f(pe_pk[t][1]);
      float pp = e0 * (lo_f(vp[2 * t]) + pe0)
               + e1 * (hi_f(vp[2 * t]) + pe1)
               + e2 * (lo_f(vp[2 * t + 1]) + pe2)
               + e3 * (hi_f(vp[2 * t + 1]) + pe3);
      pp += __shfl_xor(pp, 16);
      pp += __shfl_xor(pp, 32);
      if (quad == 0) sagg[w][c] = pp * __builtin_amdgcn_rcpf(ls);
    }
  }
  __syncthreads();   // barrier 6: sagg rows 0-7 complete

  // ---- fused Wo: out = sagg @ Wo + bo (wave w = output tile w) ----
  {
    short8 ah[4], al[4];
    #pragma unroll
    for (int s = 0; s < 4; s++) {
      f32x4 x0 = *reinterpret_cast<const f32x4*>(&sagg[l15][32 * s + quad * 8]);
      f32x4 x1 = *reinterpret_cast<const f32x4*>(&sagg[l15][32 * s + quad * 8 + 4]);
      split_frag(x0, x1, ah[s], al[s]);
    }
    f32x4 aw = {0.f, 0.f, 0.f, 0.f};
    #pragma unroll
    for (int s = 0; s < 4; s++) {
      short8 bh = *reinterpret_cast<const short8*>(fwoh + ((w * 4 + s) * 64 + lane) * 8);
      short8 bl = *reinterpret_cast<const short8*>(fwol + ((w * 4 + s) * 64 + lane) * 8);
      aw = __builtin_amdgcn_mfma_f32_16x16x32_bf16(ah[s], bh, aw, 0, 0, 0);
      aw = __builtin_amdgcn_mfma_f32_16x16x32_bf16(ah[s], bl, aw, 0, 0, 0);
      aw = __builtin_amdgcn_mfma_f32_16x16x32_bf16(al[s], bh, aw, 0, 0, 0);
    }
    int c = 16 * w + l15;
    float bb = bo[c];
    if (quad < 2) {   // rows 0-7 valid (8 nodes/block)
      #pragma unroll
      for (int r = 0; r < 4; r++)
        out[(nb0 + quad * 4 + r) * 128 + c] = aw[r] + bb;
    }
  }
}

extern "C" void kernel_launch(void* const* d_in, const int* in_sizes, int n_in,
                              void* d_out, int out_size, void* d_ws, size_t ws_size,
                              hipStream_t stream) {
  const float* x   = (const float*)d_in[0];
  const float* pos = (const float*)d_in[1];
  const int*   idx = (const int*)d_in[2];
  const float* Wq  = (const float*)d_in[3];
  const float* bq  = (const float*)d_in[4];
  const float* Wkv = (const float*)d_in[5];
  const float* bkv = (const float*)d_in[6];
  const float* Wp1 = (const float*)d_in[7];
  const float* bp1 = (const float*)d_in[8];
  const float* Wp2 = (const float*)d_in[9];
  const float* bp2 = (const float*)d_in[10];
  const float* Wa1 = (const float*)d_in[11];
  const float* ba1 = (const float*)d_in[12];
  const float* Wa2 = (const float*)d_in[13];
  const float* Wo  = (const float*)d_in[15];
  const float* bo  = (const float*)d_in[16];

  char* ws = (char*)d_ws;
  short* fqh  = (short*)(ws + 0);
  short* fql  = (short*)(ws + 49152);
  short* fwp2 = (short*)(ws + 98304);
  short* fwa1 = (short*)(ws + 131072);
  short* fwa2 = (short*)(ws + 163840);
  short* fwoh = (short*)(ws + 196608);
  short* fwol = (short*)(ws + 229376);
  float* qb = (float*)(ws + 262144);                               // 8 MB f32
  unsigned short* kb = (unsigned short*)(ws + 262144 + 8388608);   // 4 MB bf16
  unsigned short* vb = kb + NN_TOT * 128;                          // 4 MB bf16

  prep_frags<<<44, 256, 0, stream>>>(Wq, Wkv, Wp2, Wa1, Wa2, Wo,
                                     fqh, fql, fwp2, fwa1, fwa2, fwoh, fwol);
  qkv_kernel<<<768, 256, 0, stream>>>(x, bq, bkv, fqh, fql, qb, kb, vb);
  fused_attn_wo<<<2048, 512, 0, stream>>>(pos, idx, Wp1, bp1, bp2, ba1,
                                          fwp2, fwa1, fwa2, fwoh, fwol, bo,
                                          qb, kb, vb, (float*)d_out);
}

// Round 12
// 166.378 us; speedup vs baseline: 1.0449x; 1.0449x over previous
//
#include <hip/hip_runtime.h>
#include <stdint.h>

// ---------------------------------------------------------------------------
// MultiHeadPointAttention (B=2, N=8192, K=16, H=4, Cin=64, Cout=128, D=32)
//
//   prep_frags    : weights -> bf16 MFMA B-fragment layout in ws
//   qkv_kernel    : q(f32),k,v(bf16) = x @ [Wq|Wkv] + bias; per-block LDS B-slice
//   fused_attn_wo : block=512 (8 waves), NPW=1, 52 KB LDS -> 3 blocks/CU.
//                   32 KB sB cycled Wp2->Wa1->Wa2, 6 barriers. t-pair GEMM
//                   loops with fused epilogues (acc live = 8 regs). ba2
//                   dropped (cancels in softmax). v is gathered INSIDE GEMM1
//                   per t-pair and folded as vpe = bf16(pe + v), replacing
//                   pe_pk 1:1 -> zero net register delta, no long live range.
//
// R10/R11 lesson: ANY ~16-dword set held across the restage+barrier region
// gets spilled wholesale (WRITE 8->53 MB, ~44 dw/lane, in two formulations).
// Long-lived prefetch is dead; fold the consumer into an earlier epilogue
// instead. pe is only ever used as (pe - q) [same epilogue] and (v + pe)
// [softmax agg] -> store v+pe directly.
//
// MFMA 16x16x32 bf16 layouts (HW-verified):
//   A[m][k]: m = lane&15, k = (lane>>4)*8 + j
//   B[k][n]: n = lane&15, k = (lane>>4)*8 + j
//   D[r][c]: c = lane&15, r = (lane>>4)*4 + reg
// ---------------------------------------------------------------------------

typedef __attribute__((ext_vector_type(8))) short short8;
typedef __attribute__((ext_vector_type(4))) float f32x4;
typedef __attribute__((ext_vector_type(4))) unsigned int u32x4;

#define NN_TOT 16384   // B*N
#define SLW 72         // slab row stride in shorts (64 cols + 8 pad)

__device__ __forceinline__ uint32_t pk_bf16(float a, float b) {
  uint32_t r;
  asm("v_cvt_pk_bf16_f32 %0, %1, %2" : "=v"(r) : "v"(a), "v"(b));
  return r;  // low = bf16(a), high = bf16(b)
}
__device__ __forceinline__ float lo_f(uint32_t p) {
  return __builtin_bit_cast(float, p << 16);
}
__device__ __forceinline__ float hi_f(uint32_t p) {
  return __builtin_bit_cast(float, p & 0xffff0000u);
}
__device__ __forceinline__ short f2bf_rne(float f) {   // prep only
  uint32_t u = __builtin_bit_cast(uint32_t, f);
  uint32_t r = (u + 0x7FFFu + ((u >> 16) & 1u)) >> 16;
  return (short)r;
}
__device__ __forceinline__ float bf2f(unsigned short s) {
  uint32_t u = ((uint32_t)s) << 16;
  return __builtin_bit_cast(float, u);
}

__global__ __launch_bounds__(256) void prep_frags(
    const float* __restrict__ Wq, const float* __restrict__ Wkv,
    const float* __restrict__ Wp2, const float* __restrict__ Wa1,
    const float* __restrict__ Wa2, const float* __restrict__ Wo,
    short* __restrict__ fqh, short* __restrict__ fql,
    short* __restrict__ fwp2, short* __restrict__ fwa1, short* __restrict__ fwa2,
    short* __restrict__ fwoh, short* __restrict__ fwol) {
  int r = blockIdx.x * 256 + threadIdx.x;   // grid = 44*256 = 11264 exact
  if (r < 3072) {
    int t = r >> 7, rem = r & 127, s = rem >> 6, lane = rem & 63;
    int quad = lane >> 4, l15 = lane & 15;
    int col = t * 16 + l15;
    #pragma unroll
    for (int j = 0; j < 8; j++) {
      int i = 32 * s + quad * 8 + j;
      float wv = (col < 128) ? Wq[i * 128 + col] : Wkv[i * 256 + (col - 128)];
      short hi = f2bf_rne(wv);
      fqh[r * 8 + j] = hi;
      fql[r * 8 + j] = f2bf_rne(wv - bf2f((unsigned short)hi));
    }
  } else {
    int r2 = r - 3072;
    int mat = r2 >> 11;        // 0:Wp2 1:Wa1 2:Wa2 3:Wo
    int rr = r2 & 2047;
    int t = rr >> 8, rem = rr & 255, s = rem >> 6, lane = rem & 63;
    int quad = lane >> 4, l15 = lane & 15;
    int col = t * 16 + l15;
    const float* W = (mat == 0) ? Wp2 : (mat == 1) ? Wa1 : (mat == 2) ? Wa2 : Wo;
    #pragma unroll
    for (int j = 0; j < 8; j++) {
      int i = 32 * s + quad * 8 + j;
      float wv = W[i * 128 + col];
      short hi = f2bf_rne(wv);
      if (mat == 3) {
        fwoh[rr * 8 + j] = hi;
        fwol[rr * 8 + j] = f2bf_rne(wv - bf2f((unsigned short)hi));
      } else if (mat == 0) fwp2[rr * 8 + j] = hi;
      else if (mat == 1)   fwa1[rr * 8 + j] = hi;
      else                 fwa2[rr * 8 + j] = hi;
    }
  }
}

__device__ __forceinline__ void split_frag(const f32x4 x0, const f32x4 x1,
                                           short8& ah, short8& al) {
  uint32_t h01 = pk_bf16(x0[0], x0[1]);
  uint32_t h23 = pk_bf16(x0[2], x0[3]);
  uint32_t h45 = pk_bf16(x1[0], x1[1]);
  uint32_t h67 = pk_bf16(x1[2], x1[3]);
  u32x4 hh = {h01, h23, h45, h67};
  ah = __builtin_bit_cast(short8, hh);
  uint32_t l01 = pk_bf16(x0[0] - lo_f(h01), x0[1] - hi_f(h01));
  uint32_t l23 = pk_bf16(x0[2] - lo_f(h23), x0[3] - hi_f(h23));
  uint32_t l45 = pk_bf16(x1[0] - lo_f(h45), x1[1] - hi_f(h45));
  uint32_t l67 = pk_bf16(x1[2] - lo_f(h67), x1[3] - hi_f(h67));
  u32x4 ll = {l01, l23, l45, l67};
  al = __builtin_bit_cast(short8, ll);
}

// ---------------------------------------------------------------------------
// q,k,v projection. Block = 256 thr (4 waves), one section per block
// (0=q f32, 1=k bf16, 2=v bf16); section B-slice (32 KB hi+lo) in LDS.
// ---------------------------------------------------------------------------
__global__ __launch_bounds__(256) void qkv_kernel(
    const float* __restrict__ x, const float* __restrict__ bq,
    const float* __restrict__ bkv,
    const short* __restrict__ fqh, const short* __restrict__ fql,
    float* __restrict__ q, unsigned short* __restrict__ ko,
    unsigned short* __restrict__ vo) {
  __shared__ __align__(16) short sBq[16384];   // hi [0..8191], lo [8192..16383]
  const int tid = threadIdx.x;
  const int sec = blockIdx.x >> 8;             // 0..2
  const int gq = blockIdx.x & 255;
  const int w = tid >> 6, lane = tid & 63;
  const int quad = lane >> 4, l15 = lane & 15;

  {  // stage 16 KB hi + 16 KB lo of this section's frag rows
    const u32x4* sh = reinterpret_cast<const u32x4*>(fqh + sec * 8192);
    const u32x4* sl = reinterpret_cast<const u32x4*>(fql + sec * 8192);
    u32x4* dh = reinterpret_cast<u32x4*>(sBq);
    u32x4* dl = reinterpret_cast<u32x4*>(sBq + 8192);
    #pragma unroll
    for (int i = 0; i < 4; i++) {
      dh[tid + i * 256] = sh[tid + i * 256];
      dl[tid + i * 256] = sl[tid + i * 256];
    }
  }

  const int base = (gq * 4 + w) * 16;
  short8 ah[2], al[2];
  #pragma unroll
  for (int s = 0; s < 2; s++) {
    const float* xp = x + (base + l15) * 64 + 32 * s + quad * 8;
    split_frag(*reinterpret_cast<const f32x4*>(xp),
               *reinterpret_cast<const f32x4*>(xp + 4), ah[s], al[s]);
  }
  __syncthreads();

  #pragma unroll
  for (int tt = 0; tt < 8; tt++) {
    f32x4 acc = {0.f, 0.f, 0.f, 0.f};
    #pragma unroll
    for (int s = 0; s < 2; s++) {
      int rt = tt * 2 + s;
      short8 bh = *reinterpret_cast<const short8*>(sBq + rt * 512 + lane * 8);
      short8 bl = *reinterpret_cast<const short8*>(sBq + 8192 + rt * 512 + lane * 8);
      acc = __builtin_amdgcn_mfma_f32_16x16x32_bf16(ah[s], bh, acc, 0, 0, 0);
      acc = __builtin_amdgcn_mfma_f32_16x16x32_bf16(ah[s], bl, acc, 0, 0, 0);
      acc = __builtin_amdgcn_mfma_f32_16x16x32_bf16(al[s], bh, acc, 0, 0, 0);
    }
    int cl = tt * 16 + l15;                       // column within section
    if (sec == 0) {
      float bias = bq[cl];
      #pragma unroll
      for (int r = 0; r < 4; r++)
        q[(base + quad * 4 + r) * 128 + cl] = acc[r] + bias;
    } else {
      float bias = bkv[(sec - 1) * 128 + cl];
      unsigned short* dst = (sec == 1) ? ko : vo;
      #pragma unroll
      for (int r = 0; r < 4; r++) {
        float vv = acc[r] + bias;
        dst[(base + quad * 4 + r) * 128 + cl] = (unsigned short)pk_bf16(vv, vv);
      }
    }
  }
}

// ---------------------------------------------------------------------------
// Fused attention + Wo. Block = 512 thr (8 waves), 8 nodes (1/wave), 52 KB
// LDS -> 3 blocks/CU. sB (32 KB) cycled Wp2 / Wa1 / Wa2. t-pair fused
// epilogues; v folded into GEMM1 epilogue as vpe = bf16(pe + v).
// ---------------------------------------------------------------------------
__global__ __launch_bounds__(512, 6) void fused_attn_wo(
    const float* __restrict__ pos, const int* __restrict__ idx,
    const float* __restrict__ Wp1, const float* __restrict__ bp1,
    const float* __restrict__ bp2, const float* __restrict__ ba1,
    const short* __restrict__ fwp2, const short* __restrict__ fwa1,
    const short* __restrict__ fwa2,
    const short* __restrict__ fwoh, const short* __restrict__ fwol,
    const float* __restrict__ bo,
    const float* __restrict__ qg, const unsigned short* __restrict__ kg,
    const unsigned short* __restrict__ vg, float* __restrict__ out) {
  __shared__ __align__(16) short sB[16384];                   // 32 KB, cycled
  __shared__ __align__(16) unsigned short slab[8][16 * SLW];  // 18 KB half-width
  __shared__ float spd[8][16][3];
  __shared__ int sidx[8][16];
  // sagg overlays slab (8 rows x 132 f32 = 4224 B). All slab reads complete
  // before barrier 5; sagg writes follow (every wave passes barrier 5 first).
  float (*sagg)[132] = reinterpret_cast<float(*)[132]>(&slab[0][0]);

  const int tid = threadIdx.x;
  const int w = tid >> 6;
  const int lane = tid & 63;
  const int quad = lane >> 4, l15 = lane & 15;
  const int nb0 = blockIdx.x * 8;
  const int node = nb0 + w;
  unsigned short* myslab = &slab[w][0];

  // ---- neighbor idx + pos_diff (wave-private) ----
  if (lane < 16) {
    int ji = idx[node * 16 + lane];
    int jn = ((node >> 13) << 13) + ji;
    sidx[w][lane] = jn;
    spd[w][lane][0] = pos[node * 3 + 0] - pos[jn * 3 + 0];
    spd[w][lane][1] = pos[node * 3 + 1] - pos[jn * 3 + 1];
    spd[w][lane][2] = pos[node * 3 + 2] - pos[jn * 3 + 2];
  }

  // ---- stage sB <- Wp2 frags (32 KB, all threads) ----
  {
    const u32x4* s4 = reinterpret_cast<const u32x4*>(fwp2);
    u32x4* d4 = reinterpret_cast<u32x4*>(sB);
    #pragma unroll
    for (int i = 0; i < 4; i++) d4[tid + i * 512] = s4[tid + i * 512];
  }

  // ---- pos MLP layer 1 -> slab (two column-phases) -> aP frags ----
  short8 aP[4];
  #pragma unroll
  for (int p = 0; p < 2; p++) {
    const int c = lane + p * 64;           // channel; slab col = lane
    float wp0 = Wp1[c], wp1 = Wp1[128 + c], wp2v = Wp1[256 + c], bb = bp1[c];
    #pragma unroll
    for (int m = 0; m < 16; m++) {
      float h = fmaxf(bb + spd[w][m][0] * wp0 + spd[w][m][1] * wp1 +
                           spd[w][m][2] * wp2v, 0.f);
      myslab[m * SLW + lane] = (unsigned short)pk_bf16(h, h);
    }
    #pragma unroll
    for (int ss = 0; ss < 2; ss++)
      aP[p * 2 + ss] = *reinterpret_cast<const short8*>(
          myslab + l15 * SLW + 32 * ss + quad * 8);
  }
  __syncthreads();   // barrier 1: sB = Wp2 ready

  // ---- gathers: k (packed bf16) + q in C/D layout (hide under GEMM1) ----
  short8 k_pk[4];
  float qv[8];
  int vb[4];
  {
    const unsigned short* kp = kg + sidx[w][l15] * 128;
    #pragma unroll
    for (int s = 0; s < 4; s++)
      k_pk[s] = *reinterpret_cast<const short8*>(kp + 32 * s + quad * 8);
    const float* qrow = qg + node * 128;
    #pragma unroll
    for (int t = 0; t < 8; t++) qv[t] = qrow[16 * t + l15];
    #pragma unroll
    for (int r = 0; r < 4; r++) vb[r] = sidx[w][quad * 4 + r] * 128;
  }

  uint32_t vpe_pk[8][2];   // bf16(pe + v) pairs — replaces pe_pk 1:1
  short8 a2[4];

  // ---- GEMM1 (t-pairs, fused pe/vpe epilogue): pos_enc = pos_hidden @ Wp2.
  //      v gathered per t-pair (8 transient ushorts), consumed same pair. ----
  #pragma unroll
  for (int p = 0; p < 2; p++) {
    #pragma unroll
    for (int half = 0; half < 2; half++) {
      const int t0 = p * 4 + half * 2, t1 = t0 + 1;
      // v gather for these two tiles; latency hides behind the MFMA chain
      const int c0 = 16 * t0 + l15, c1 = 16 * t1 + l15;
      unsigned short v00 = vg[vb[0] + c0], v01 = vg[vb[1] + c0];
      unsigned short v02 = vg[vb[2] + c0], v03 = vg[vb[3] + c0];
      unsigned short v10 = vg[vb[0] + c1], v11 = vg[vb[1] + c1];
      unsigned short v12 = vg[vb[2] + c1], v13 = vg[vb[3] + c1];
      f32x4 aa = {0.f, 0.f, 0.f, 0.f}, ab = {0.f, 0.f, 0.f, 0.f};
      #pragma unroll
      for (int s = 0; s < 4; s++) {
        short8 b0 = *reinterpret_cast<const short8*>(sB + ((t0 * 4 + s) * 64 + lane) * 8);
        short8 b1 = *reinterpret_cast<const short8*>(sB + ((t1 * 4 + s) * 64 + lane) * 8);
        aa = __builtin_amdgcn_mfma_f32_16x16x32_bf16(aP[s], b0, aa, 0, 0, 0);
        ab = __builtin_amdgcn_mfma_f32_16x16x32_bf16(aP[s], b1, ab, 0, 0, 0);
      }
      #pragma unroll
      for (int e = 0; e < 2; e++) {
        const int t = e ? t1 : t0;
        const f32x4 ac = e ? ab : aa;
        float bb = bp2[16 * t + l15];
        float f0 = ac[0] + bb, f1 = ac[1] + bb, f2 = ac[2] + bb, f3 = ac[3] + bb;
        unsigned short w0 = e ? v10 : v00, w1 = e ? v11 : v01;
        unsigned short w2 = e ? v12 : v02, w3 = e ? v13 : v03;
        vpe_pk[t][0] = pk_bf16(f0 + bf2f(w0), f1 + bf2f(w1));
        vpe_pk[t][1] = pk_bf16(f2 + bf2f(w2), f3 + bf2f(w3));
        float q_ = qv[t];
        uint32_t g01 = pk_bf16(f0 - q_, f1 - q_);
        uint32_t g23 = pk_bf16(f2 - q_, f3 - q_);
        int cl = 16 * (t & 3) + l15;
        myslab[(quad * 4 + 0) * SLW + cl] = (unsigned short)g01;
        myslab[(quad * 4 + 1) * SLW + cl] = (unsigned short)(g01 >> 16);
        myslab[(quad * 4 + 2) * SLW + cl] = (unsigned short)g23;
        myslab[(quad * 4 + 3) * SLW + cl] = (unsigned short)(g23 >> 16);
      }
    }
    // build a2 for this phase: rel = k + (pe - q)
    #pragma unroll
    for (int ss = 0; ss < 2; ss++) {
      int s = p * 2 + ss;
      short8 pq = *reinterpret_cast<const short8*>(
          myslab + l15 * SLW + 32 * ss + quad * 8);
      short8 kk = k_pk[s];
      u32x4 av = {pk_bf16(bf2f((unsigned short)kk[0]) + bf2f((unsigned short)pq[0]),
                          bf2f((unsigned short)kk[1]) + bf2f((unsigned short)pq[1])),
                  pk_bf16(bf2f((unsigned short)kk[2]) + bf2f((unsigned short)pq[2]),
                          bf2f((unsigned short)kk[3]) + bf2f((unsigned short)pq[3])),
                  pk_bf16(bf2f((unsigned short)kk[4]) + bf2f((unsigned short)pq[4]),
                          bf2f((unsigned short)kk[5]) + bf2f((unsigned short)pq[5])),
                  pk_bf16(bf2f((unsigned short)kk[6]) + bf2f((unsigned short)pq[6]),
                          bf2f((unsigned short)kk[7]) + bf2f((unsigned short)pq[7]))};
      a2[s] = __builtin_bit_cast(short8, av);
    }
  }
  __syncthreads();   // barrier 2: all waves done reading Wp2

  // ---- restage sB <- Wa1 ----
  {
    const u32x4* s4 = reinterpret_cast<const u32x4*>(fwa1);
    u32x4* d4 = reinterpret_cast<u32x4*>(sB);
    #pragma unroll
    for (int i = 0; i < 4; i++) d4[tid + i * 512] = s4[tid + i * 512];
  }
  __syncthreads();   // barrier 3: sB = Wa1 ready

  // ---- GEMM2 (t-pairs, fused relu epilogue): hidden = relu(rel@Wa1+ba1) ----
  short8 a3[4];
  #pragma unroll
  for (int p = 0; p < 2; p++) {
    #pragma unroll
    for (int half = 0; half < 2; half++) {
      const int t0 = p * 4 + half * 2, t1 = t0 + 1;
      f32x4 aa = {0.f, 0.f, 0.f, 0.f}, ab = {0.f, 0.f, 0.f, 0.f};
      #pragma unroll
      for (int s = 0; s < 4; s++) {
        short8 b0 = *reinterpret_cast<const short8*>(sB + ((t0 * 4 + s) * 64 + lane) * 8);
        short8 b1 = *reinterpret_cast<const short8*>(sB + ((t1 * 4 + s) * 64 + lane) * 8);
        aa = __builtin_amdgcn_mfma_f32_16x16x32_bf16(a2[s], b0, aa, 0, 0, 0);
        ab = __builtin_amdgcn_mfma_f32_16x16x32_bf16(a2[s], b1, ab, 0, 0, 0);
      }
      #pragma unroll
      for (int e = 0; e < 2; e++) {
        const int t = e ? t1 : t0;
        const f32x4 ac = e ? ab : aa;
        float bb = ba1[16 * t + l15];
        uint32_t p01 = pk_bf16(fmaxf(ac[0] + bb, 0.f), fmaxf(ac[1] + bb, 0.f));
        uint32_t p23 = pk_bf16(fmaxf(ac[2] + bb, 0.f), fmaxf(ac[3] + bb, 0.f));
        int cl = 16 * (t & 3) + l15;
        myslab[(quad * 4 + 0) * SLW + cl] = (unsigned short)p01;
        myslab[(quad * 4 + 1) * SLW + cl] = (unsigned short)(p01 >> 16);
        myslab[(quad * 4 + 2) * SLW + cl] = (unsigned short)p23;
        myslab[(quad * 4 + 3) * SLW + cl] = (unsigned short)(p23 >> 16);
      }
    }
    #pragma unroll
    for (int ss = 0; ss < 2; ss++)
      a3[p * 2 + ss] = *reinterpret_cast<const short8*>(
          myslab + l15 * SLW + 32 * ss + quad * 8);
  }
  __syncthreads();   // barrier 4: all waves done reading Wa1

  // ---- restage sB <- Wa2 ----
  {
    const u32x4* s4 = reinterpret_cast<const u32x4*>(fwa2);
    u32x4* d4 = reinterpret_cast<u32x4*>(sB);
    #pragma unroll
    for (int i = 0; i < 4; i++) d4[tid + i * 512] = s4[tid + i * 512];
  }
  __syncthreads();   // barrier 5: sB = Wa2 ready; all slab reads done

  // ---- GEMM3 (t-pairs, fused softmax+agg epilogue). ba2 cancels.
  //      No global loads here: v already folded into vpe_pk. ----
  #pragma unroll
  for (int tp = 0; tp < 4; tp++) {
    const int t0 = tp * 2, t1 = t0 + 1;
    f32x4 aa = {0.f, 0.f, 0.f, 0.f}, ab = {0.f, 0.f, 0.f, 0.f};
    #pragma unroll
    for (int s = 0; s < 4; s++) {
      short8 b0 = *reinterpret_cast<const short8*>(sB + ((t0 * 4 + s) * 64 + lane) * 8);
      short8 b1 = *reinterpret_cast<const short8*>(sB + ((t1 * 4 + s) * 64 + lane) * 8);
      aa = __builtin_amdgcn_mfma_f32_16x16x32_bf16(a3[s], b0, aa, 0, 0, 0);
      ab = __builtin_amdgcn_mfma_f32_16x16x32_bf16(a3[s], b1, ab, 0, 0, 0);
    }
    #pragma unroll
    for (int e = 0; e < 2; e++) {
      const int t = e ? t1 : t0;
      const f32x4 ac = e ? ab : aa;
      int c = 16 * t + l15;
      float g0 = ac[0], g1 = ac[1], g2 = ac[2], g3 = ac[3];
      float mx = fmaxf(fmaxf(g0, g1), fmaxf(g2, g3));
      mx = fmaxf(mx, __shfl_xor(mx, 16));
      mx = fmaxf(mx, __shfl_xor(mx, 32));
      float e0 = __expf(g0 - mx), e1 = __expf(g1 - mx);
      float e2 = __expf(g2 - mx), e3 = __expf(g3 - mx);
      float ls = e0 + e1 + e2 + e3;
      ls += __shfl_xor(ls, 16);
      ls += __shfl_xor(ls, 32);
      float pp = e0 * lo_f(vpe_pk[t][0]) + e1 * hi_f(vpe_pk[t][0])
               + e2 * lo_f(vpe_pk[t][1]) + e3 * hi_f(vpe_pk[t][1]);
      pp += __shfl_xor(pp, 16);
      pp += __shfl_xor(pp, 32);
      if (quad == 0) sagg[w][c] = pp * __builtin_amdgcn_rcpf(ls);
    }
  }
  __syncthreads();   // barrier 6: sagg rows 0-7 complete

  // ---- fused Wo: out = sagg @ Wo + bo (wave w = output tile w) ----
  {
    short8 ah[4], al[4];
    #pragma unroll
    for (int s = 0; s < 4; s++) {
      f32x4 x0 = *reinterpret_cast<const f32x4*>(&sagg[l15][32 * s + quad * 8]);
      f32x4 x1 = *reinterpret_cast<const f32x4*>(&sagg[l15][32 * s + quad * 8 + 4]);
      split_frag(x0, x1, ah[s], al[s]);
    }
    f32x4 aw = {0.f, 0.f, 0.f, 0.f};
    #pragma unroll
    for (int s = 0; s < 4; s++) {
      short8 bh = *reinterpret_cast<const short8*>(fwoh + ((w * 4 + s) * 64 + lane) * 8);
      short8 bl = *reinterpret_cast<const short8*>(fwol + ((w * 4 + s) * 64 + lane) * 8);
      aw = __builtin_amdgcn_mfma_f32_16x16x32_bf16(ah[s], bh, aw, 0, 0, 0);
      aw = __builtin_amdgcn_mfma_f32_16x16x32_bf16(ah[s], bl, aw, 0, 0, 0);
      aw = __builtin_amdgcn_mfma_f32_16x16x32_bf16(al[s], bh, aw, 0, 0, 0);
    }
    int c = 16 * w + l15;
    float bb = bo[c];
    if (quad < 2) {   // rows 0-7 valid (8 nodes/block)
      #pragma unroll
      for (int r = 0; r < 4; r++)
        out[(nb0 + quad * 4 + r) * 128 + c] = aw[r] + bb;
    }
  }
}

extern "C" void kernel_launch(void* const* d_in, const int* in_sizes, int n_in,
                              void* d_out, int out_size, void* d_ws, size_t ws_size,
                              hipStream_t stream) {
  const float* x   = (const float*)d_in[0];
  const float* pos = (const float*)d_in[1];
  const int*   idx = (const int*)d_in[2];
  const float* Wq  = (const float*)d_in[3];
  const float* bq  = (const float*)d_in[4];
  const float* Wkv = (const float*)d_in[5];
  const float* bkv = (const float*)d_in[6];
  const float* Wp1 = (const float*)d_in[7];
  const float* bp1 = (const float*)d_in[8];
  const float* Wp2 = (const float*)d_in[9];
  const float* bp2 = (const float*)d_in[10];
  const float* Wa1 = (const float*)d_in[11];
  const float* ba1 = (const float*)d_in[12];
  const float* Wa2 = (const float*)d_in[13];
  const float* Wo  = (const float*)d_in[15];
  const float* bo  = (const float*)d_in[16];

  char* ws = (char*)d_ws;
  short* fqh  = (short*)(ws + 0);
  short* fql  = (short*)(ws + 49152);
  short* fwp2 = (short*)(ws + 98304);
  short* fwa1 = (short*)(ws + 131072);
  short* fwa2 = (short*)(ws + 163840);
  short* fwoh = (short*)(ws + 196608);
  short* fwol = (short*)(ws + 229376);
  float* qb = (float*)(ws + 262144);                               // 8 MB f32
  unsigned short* kb = (unsigned short*)(ws + 262144 + 8388608);   // 4 MB bf16
  unsigned short* vb = kb + NN_TOT * 128;                          // 4 MB bf16

  prep_frags<<<44, 256, 0, stream>>>(Wq, Wkv, Wp2, Wa1, Wa2, Wo,
                                     fqh, fql, fwp2, fwa1, fwa2, fwoh, fwol);
  qkv_kernel<<<768, 256, 0, stream>>>(x, bq, bkv, fqh, fql, qb, kb, vb);
  fused_attn_wo<<<2048, 512, 0, stream>>>(pos, idx, Wp1, bp1, bp2, ba1,
                                          fwp2, fwa1, fwa2, fwoh, fwol, bo,
                                          qb, kb, vb, (float*)d_out);
}

// Round 13
// 160.676 us; speedup vs baseline: 1.0820x; 1.0355x over previous
//
#include <hip/hip_runtime.h>
#include <stdint.h>

// ---------------------------------------------------------------------------
// MultiHeadPointAttention (B=2, N=8192, K=16, H=4, Cin=64, Cout=128, D=32)
//
//   qkv_prep (800 blocks):
//     blocks 0..767  : q(f32),k,v(bf16) = x @ [Wq|Wkv] + bias. The section's
//                      B-slice is converted INLINE from f32 weights into LDS
//                      (hi/lo bf16) — no separate prep pass needed for qkv.
//     blocks 768..799: weight->frag conversion for the fused kernel
//                      (fwp2 / fwa1 / fwa2 / fwoh / fwol).
//   fused_attn_wo : unchanged from R12. block=512 (8 waves), NPW=1, 52 KB
//                   LDS -> 3 blocks/CU. 32 KB sB cycled Wp2->Wa1->Wa2,
//                   6 barriers, t-pair fused epilogues, v folded as
//                   vpe = bf16(pe + v) in GEMM1's epilogue.
//
// R12 lesson: vpe_pk (16 dw) crossing barriers 2-5 partially spills (~8 MB
// writes) — structural to any >8dw live set in that region; tolerated.
// R13 experiment: 3 launches -> 2, to decompose the invariant ~90 us side
// residue (launch/gap overhead vs harness-fixed reset time).
//
// MFMA 16x16x32 bf16 layouts (HW-verified):
//   A[m][k]: m = lane&15, k = (lane>>4)*8 + j
//   B[k][n]: n = lane&15, k = (lane>>4)*8 + j
//   D[r][c]: c = lane&15, r = (lane>>4)*4 + reg
// ---------------------------------------------------------------------------

typedef __attribute__((ext_vector_type(8))) short short8;
typedef __attribute__((ext_vector_type(4))) float f32x4;
typedef __attribute__((ext_vector_type(4))) unsigned int u32x4;

#define NN_TOT 16384   // B*N
#define SLW 72         // slab row stride in shorts (64 cols + 8 pad)

__device__ __forceinline__ uint32_t pk_bf16(float a, float b) {
  uint32_t r;
  asm("v_cvt_pk_bf16_f32 %0, %1, %2" : "=v"(r) : "v"(a), "v"(b));
  return r;  // low = bf16(a), high = bf16(b)
}
__device__ __forceinline__ float lo_f(uint32_t p) {
  return __builtin_bit_cast(float, p << 16);
}
__device__ __forceinline__ float hi_f(uint32_t p) {
  return __builtin_bit_cast(float, p & 0xffff0000u);
}
__device__ __forceinline__ float bf2f(unsigned short s) {
  uint32_t u = ((uint32_t)s) << 16;
  return __builtin_bit_cast(float, u);
}

__device__ __forceinline__ void split_frag(const f32x4 x0, const f32x4 x1,
                                           short8& ah, short8& al) {
  uint32_t h01 = pk_bf16(x0[0], x0[1]);
  uint32_t h23 = pk_bf16(x0[2], x0[3]);
  uint32_t h45 = pk_bf16(x1[0], x1[1]);
  uint32_t h67 = pk_bf16(x1[2], x1[3]);
  u32x4 hh = {h01, h23, h45, h67};
  ah = __builtin_bit_cast(short8, hh);
  uint32_t l01 = pk_bf16(x0[0] - lo_f(h01), x0[1] - hi_f(h01));
  uint32_t l23 = pk_bf16(x0[2] - lo_f(h23), x0[3] - hi_f(h23));
  uint32_t l45 = pk_bf16(x1[0] - lo_f(h45), x1[1] - hi_f(h45));
  uint32_t l67 = pk_bf16(x1[2] - lo_f(h67), x1[3] - hi_f(h67));
  u32x4 ll = {l01, l23, l45, l67};
  al = __builtin_bit_cast(short8, ll);
}

// ---------------------------------------------------------------------------
// Merged q/k/v projection + fused-weight prep. Blocks 0..767: qkv (one
// section per block: 0=q f32, 1=k bf16, 2=v bf16; B-slice inline-converted
// from f32 into 32 KB LDS). Blocks 768..799: frag prep for fused.
// ---------------------------------------------------------------------------
__global__ __launch_bounds__(256) void qkv_prep(
    const float* __restrict__ x, const float* __restrict__ bq,
    const float* __restrict__ bkv,
    const float* __restrict__ Wq, const float* __restrict__ Wkv,
    const float* __restrict__ Wp2, const float* __restrict__ Wa1,
    const float* __restrict__ Wa2, const float* __restrict__ Wo,
    short* __restrict__ fwp2, short* __restrict__ fwa1, short* __restrict__ fwa2,
    short* __restrict__ fwoh, short* __restrict__ fwol,
    float* __restrict__ q, unsigned short* __restrict__ ko,
    unsigned short* __restrict__ vo) {
  const int tid = threadIdx.x;

  if (blockIdx.x >= 768) {
    // ---- prep path: fused-kernel weight frags (128x128 mats) ----
    int r2 = (blockIdx.x - 768) * 256 + tid;   // 0..8191
    int mat = r2 >> 11;        // 0:Wp2 1:Wa1 2:Wa2 3:Wo
    int rr = r2 & 2047;
    int t = rr >> 8, rem = rr & 255, s = rem >> 6, lane = rem & 63;
    int quad = lane >> 4, l15 = lane & 15;
    int col = t * 16 + l15;
    const float* W = (mat == 0) ? Wp2 : (mat == 1) ? Wa1 : (mat == 2) ? Wa2 : Wo;
    #pragma unroll
    for (int j = 0; j < 8; j++) {
      int i = 32 * s + quad * 8 + j;
      float wv = W[i * 128 + col];
      unsigned short hs = (unsigned short)pk_bf16(wv, wv);
      if (mat == 3) {
        float res = wv - bf2f(hs);
        fwoh[rr * 8 + j] = (short)hs;
        fwol[rr * 8 + j] = (short)(unsigned short)pk_bf16(res, res);
      } else if (mat == 0) fwp2[rr * 8 + j] = (short)hs;
      else if (mat == 1)   fwa1[rr * 8 + j] = (short)hs;
      else                 fwa2[rr * 8 + j] = (short)hs;
    }
    return;
  }

  // ---- qkv path ----
  __shared__ __align__(16) short sBq[16384];   // hi [0..8191], lo [8192..16383]
  const int sec = blockIdx.x >> 8;             // 0..2
  const int gq = blockIdx.x & 255;
  const int w = tid >> 6, lane = tid & 63;
  const int quad = lane >> 4, l15 = lane & 15;

  {  // inline-convert this section's B-slice (1024 frag rows) from f32
    #pragma unroll
    for (int i = 0; i < 4; i++) {
      int rl = tid + i * 256;                  // local frag row 0..1023
      int tl = rl >> 7, rem = rl & 127, sk = rem >> 6, lr = rem & 63;
      int col = (sec << 7) + tl * 16 + (lr & 15);   // global col 0..383
      int ik0 = 32 * sk + (lr >> 4) * 8;
      const float* Wp = (sec == 0) ? Wq : Wkv;
      int stride = (sec == 0) ? 128 : 256;
      int coff = (sec == 0) ? col : (col - 128);
      #pragma unroll
      for (int j = 0; j < 8; j++) {
        float wv = Wp[(ik0 + j) * stride + coff];
        unsigned short hs = (unsigned short)pk_bf16(wv, wv);
        float res = wv - bf2f(hs);
        sBq[rl * 8 + j] = (short)hs;
        sBq[8192 + rl * 8 + j] = (short)(unsigned short)pk_bf16(res, res);
      }
    }
  }

  const int base = (gq * 4 + w) * 16;
  short8 ah[2], al[2];
  #pragma unroll
  for (int s = 0; s < 2; s++) {
    const float* xp = x + (base + l15) * 64 + 32 * s + quad * 8;
    split_frag(*reinterpret_cast<const f32x4*>(xp),
               *reinterpret_cast<const f32x4*>(xp + 4), ah[s], al[s]);
  }
  __syncthreads();

  #pragma unroll
  for (int tt = 0; tt < 8; tt++) {
    f32x4 acc = {0.f, 0.f, 0.f, 0.f};
    #pragma unroll
    for (int s = 0; s < 2; s++) {
      int rt = tt * 2 + s;
      short8 bh = *reinterpret_cast<const short8*>(sBq + rt * 512 + lane * 8);
      short8 bl = *reinterpret_cast<const short8*>(sBq + 8192 + rt * 512 + lane * 8);
      acc = __builtin_amdgcn_mfma_f32_16x16x32_bf16(ah[s], bh, acc, 0, 0, 0);
      acc = __builtin_amdgcn_mfma_f32_16x16x32_bf16(ah[s], bl, acc, 0, 0, 0);
      acc = __builtin_amdgcn_mfma_f32_16x16x32_bf16(al[s], bh, acc, 0, 0, 0);
    }
    int cl = tt * 16 + l15;                       // column within section
    if (sec == 0) {
      float bias = bq[cl];
      #pragma unroll
      for (int r = 0; r < 4; r++)
        q[(base + quad * 4 + r) * 128 + cl] = acc[r] + bias;
    } else {
      float bias = bkv[(sec - 1) * 128 + cl];
      unsigned short* dst = (sec == 1) ? ko : vo;
      #pragma unroll
      for (int r = 0; r < 4; r++) {
        float vv = acc[r] + bias;
        dst[(base + quad * 4 + r) * 128 + cl] = (unsigned short)pk_bf16(vv, vv);
      }
    }
  }
}

// ---------------------------------------------------------------------------
// Fused attention + Wo (unchanged from R12). Block = 512 thr (8 waves),
// 8 nodes (1/wave), 52 KB LDS -> 3 blocks/CU. sB (32 KB) cycled.
// ---------------------------------------------------------------------------
__global__ __launch_bounds__(512, 6) void fused_attn_wo(
    const float* __restrict__ pos, const int* __restrict__ idx,
    const float* __restrict__ Wp1, const float* __restrict__ bp1,
    const float* __restrict__ bp2, const float* __restrict__ ba1,
    const short* __restrict__ fwp2, const short* __restrict__ fwa1,
    const short* __restrict__ fwa2,
    const short* __restrict__ fwoh, const short* __restrict__ fwol,
    const float* __restrict__ bo,
    const float* __restrict__ qg, const unsigned short* __restrict__ kg,
    const unsigned short* __restrict__ vg, float* __restrict__ out) {
  __shared__ __align__(16) short sB[16384];                   // 32 KB, cycled
  __shared__ __align__(16) unsigned short slab[8][16 * SLW];  // 18 KB half-width
  __shared__ float spd[8][16][3];
  __shared__ int sidx[8][16];
  float (*sagg)[132] = reinterpret_cast<float(*)[132]>(&slab[0][0]);

  const int tid = threadIdx.x;
  const int w = tid >> 6;
  const int lane = tid & 63;
  const int quad = lane >> 4, l15 = lane & 15;
  const int nb0 = blockIdx.x * 8;
  const int node = nb0 + w;
  unsigned short* myslab = &slab[w][0];

  // ---- neighbor idx + pos_diff (wave-private) ----
  if (lane < 16) {
    int ji = idx[node * 16 + lane];
    int jn = ((node >> 13) << 13) + ji;
    sidx[w][lane] = jn;
    spd[w][lane][0] = pos[node * 3 + 0] - pos[jn * 3 + 0];
    spd[w][lane][1] = pos[node * 3 + 1] - pos[jn * 3 + 1];
    spd[w][lane][2] = pos[node * 3 + 2] - pos[jn * 3 + 2];
  }

  // ---- stage sB <- Wp2 frags (32 KB, all threads) ----
  {
    const u32x4* s4 = reinterpret_cast<const u32x4*>(fwp2);
    u32x4* d4 = reinterpret_cast<u32x4*>(sB);
    #pragma unroll
    for (int i = 0; i < 4; i++) d4[tid + i * 512] = s4[tid + i * 512];
  }

  // ---- pos MLP layer 1 -> slab (two column-phases) -> aP frags ----
  short8 aP[4];
  #pragma unroll
  for (int p = 0; p < 2; p++) {
    const int c = lane + p * 64;           // channel; slab col = lane
    float wp0 = Wp1[c], wp1 = Wp1[128 + c], wp2v = Wp1[256 + c], bb = bp1[c];
    #pragma unroll
    for (int m = 0; m < 16; m++) {
      float h = fmaxf(bb + spd[w][m][0] * wp0 + spd[w][m][1] * wp1 +
                           spd[w][m][2] * wp2v, 0.f);
      myslab[m * SLW + lane] = (unsigned short)pk_bf16(h, h);
    }
    #pragma unroll
    for (int ss = 0; ss < 2; ss++)
      aP[p * 2 + ss] = *reinterpret_cast<const short8*>(
          myslab + l15 * SLW + 32 * ss + quad * 8);
  }
  __syncthreads();   // barrier 1: sB = Wp2 ready

  // ---- gathers: k (packed bf16) + q in C/D layout (hide under GEMM1) ----
  short8 k_pk[4];
  float qv[8];
  int vb[4];
  {
    const unsigned short* kp = kg + sidx[w][l15] * 128;
    #pragma unroll
    for (int s = 0; s < 4; s++)
      k_pk[s] = *reinterpret_cast<const short8*>(kp + 32 * s + quad * 8);
    const float* qrow = qg + node * 128;
    #pragma unroll
    for (int t = 0; t < 8; t++) qv[t] = qrow[16 * t + l15];
    #pragma unroll
    for (int r = 0; r < 4; r++) vb[r] = sidx[w][quad * 4 + r] * 128;
  }

  uint32_t vpe_pk[8][2];   // bf16(pe + v) pairs
  short8 a2[4];

  // ---- GEMM1 (t-pairs, fused pe/vpe epilogue): pos_enc = pos_hidden @ Wp2.
  //      v gathered per t-pair (8 transient ushorts), consumed same pair. ----
  #pragma unroll
  for (int p = 0; p < 2; p++) {
    #pragma unroll
    for (int half = 0; half < 2; half++) {
      const int t0 = p * 4 + half * 2, t1 = t0 + 1;
      const int c0 = 16 * t0 + l15, c1 = 16 * t1 + l15;
      unsigned short v00 = vg[vb[0] + c0], v01 = vg[vb[1] + c0];
      unsigned short v02 = vg[vb[2] + c0], v03 = vg[vb[3] + c0];
      unsigned short v10 = vg[vb[0] + c1], v11 = vg[vb[1] + c1];
      unsigned short v12 = vg[vb[2] + c1], v13 = vg[vb[3] + c1];
      f32x4 aa = {0.f, 0.f, 0.f, 0.f}, ab = {0.f, 0.f, 0.f, 0.f};
      #pragma unroll
      for (int s = 0; s < 4; s++) {
        short8 b0 = *reinterpret_cast<const short8*>(sB + ((t0 * 4 + s) * 64 + lane) * 8);
        short8 b1 = *reinterpret_cast<const short8*>(sB + ((t1 * 4 + s) * 64 + lane) * 8);
        aa = __builtin_amdgcn_mfma_f32_16x16x32_bf16(aP[s], b0, aa, 0, 0, 0);
        ab = __builtin_amdgcn_mfma_f32_16x16x32_bf16(aP[s], b1, ab, 0, 0, 0);
      }
      #pragma unroll
      for (int e = 0; e < 2; e++) {
        const int t = e ? t1 : t0;
        const f32x4 ac = e ? ab : aa;
        float bb = bp2[16 * t + l15];
        float f0 = ac[0] + bb, f1 = ac[1] + bb, f2 = ac[2] + bb, f3 = ac[3] + bb;
        unsigned short w0 = e ? v10 : v00, w1 = e ? v11 : v01;
        unsigned short w2 = e ? v12 : v02, w3 = e ? v13 : v03;
        vpe_pk[t][0] = pk_bf16(f0 + bf2f(w0), f1 + bf2f(w1));
        vpe_pk[t][1] = pk_bf16(f2 + bf2f(w2), f3 + bf2f(w3));
        float q_ = qv[t];
        uint32_t g01 = pk_bf16(f0 - q_, f1 - q_);
        uint32_t g23 = pk_bf16(f2 - q_, f3 - q_);
        int cl = 16 * (t & 3) + l15;
        myslab[(quad * 4 + 0) * SLW + cl] = (unsigned short)g01;
        myslab[(quad * 4 + 1) * SLW + cl] = (unsigned short)(g01 >> 16);
        myslab[(quad * 4 + 2) * SLW + cl] = (unsigned short)g23;
        myslab[(quad * 4 + 3) * SLW + cl] = (unsigned short)(g23 >> 16);
      }
    }
    // build a2 for this phase: rel = k + (pe - q)
    #pragma unroll
    for (int ss = 0; ss < 2; ss++) {
      int s = p * 2 + ss;
      short8 pq = *reinterpret_cast<const short8*>(
          myslab + l15 * SLW + 32 * ss + quad * 8);
      short8 kk = k_pk[s];
      u32x4 av = {pk_bf16(bf2f((unsigned short)kk[0]) + bf2f((unsigned short)pq[0]),
                          bf2f((unsigned short)kk[1]) + bf2f((unsigned short)pq[1])),
                  pk_bf16(bf2f((unsigned short)kk[2]) + bf2f((unsigned short)pq[2]),
                          bf2f((unsigned short)kk[3]) + bf2f((unsigned short)pq[3])),
                  pk_bf16(bf2f((unsigned short)kk[4]) + bf2f((unsigned short)pq[4]),
                          bf2f((unsigned short)kk[5]) + bf2f((unsigned short)pq[5])),
                  pk_bf16(bf2f((unsigned short)kk[6]) + bf2f((unsigned short)pq[6]),
                          bf2f((unsigned short)kk[7]) + bf2f((unsigned short)pq[7]))};
      a2[s] = __builtin_bit_cast(short8, av);
    }
  }
  __syncthreads();   // barrier 2: all waves done reading Wp2

  // ---- restage sB <- Wa1 ----
  {
    const u32x4* s4 = reinterpret_cast<const u32x4*>(fwa1);
    u32x4* d4 = reinterpret_cast<u32x4*>(sB);
    #pragma unroll
    for (int i = 0; i < 4; i++) d4[tid + i * 512] = s4[tid + i * 512];
  }
  __syncthreads();   // barrier 3: sB = Wa1 ready

  // ---- GEMM2 (t-pairs, fused relu epilogue): hidden = relu(rel@Wa1+ba1) ----
  short8 a3[4];
  #pragma unroll
  for (int p = 0; p < 2; p++) {
    #pragma unroll
    for (int half = 0; half < 2; half++) {
      const int t0 = p * 4 + half * 2, t1 = t0 + 1;
      f32x4 aa = {0.f, 0.f, 0.f, 0.f}, ab = {0.f, 0.f, 0.f, 0.f};
      #pragma unroll
      for (int s = 0; s < 4; s++) {
        short8 b0 = *reinterpret_cast<const short8*>(sB + ((t0 * 4 + s) * 64 + lane) * 8);
        short8 b1 = *reinterpret_cast<const short8*>(sB + ((t1 * 4 + s) * 64 + lane) * 8);
        aa = __builtin_amdgcn_mfma_f32_16x16x32_bf16(a2[s], b0, aa, 0, 0, 0);
        ab = __builtin_amdgcn_mfma_f32_16x16x32_bf16(a2[s], b1, ab, 0, 0, 0);
      }
      #pragma unroll
      for (int e = 0; e < 2; e++) {
        const int t = e ? t1 : t0;
        const f32x4 ac = e ? ab : aa;
        float bb = ba1[16 * t + l15];
        uint32_t p01 = pk_bf16(fmaxf(ac[0] + bb, 0.f), fmaxf(ac[1] + bb, 0.f));
        uint32_t p23 = pk_bf16(fmaxf(ac[2] + bb, 0.f), fmaxf(ac[3] + bb, 0.f));
        int cl = 16 * (t & 3) + l15;
        myslab[(quad * 4 + 0) * SLW + cl] = (unsigned short)p01;
        myslab[(quad * 4 + 1) * SLW + cl] = (unsigned short)(p01 >> 16);
        myslab[(quad * 4 + 2) * SLW + cl] = (unsigned short)p23;
        myslab[(quad * 4 + 3) * SLW + cl] = (unsigned short)(p23 >> 16);
      }
    }
    #pragma unroll
    for (int ss = 0; ss < 2; ss++)
      a3[p * 2 + ss] = *reinterpret_cast<const short8*>(
          myslab + l15 * SLW + 32 * ss + quad * 8);
  }
  __syncthreads();   // barrier 4: all waves done reading Wa1

  // ---- restage sB <- Wa2 ----
  {
    const u32x4* s4 = reinterpret_cast<const u32x4*>(fwa2);
    u32x4* d4 = reinterpret_cast<u32x4*>(sB);
    #pragma unroll
    for (int i = 0; i < 4; i++) d4[tid + i * 512] = s4[tid + i * 512];
  }
  __syncthreads();   // barrier 5: sB = Wa2 ready; all slab reads done

  // ---- GEMM3 (t-pairs, fused softmax+agg epilogue). ba2 cancels.
  //      No global loads here: v already folded into vpe_pk. ----
  #pragma unroll
  for (int tp = 0; tp < 4; tp++) {
    const int t0 = tp * 2, t1 = t0 + 1;
    f32x4 aa = {0.f, 0.f, 0.f, 0.f}, ab = {0.f, 0.f, 0.f, 0.f};
    #pragma unroll
    for (int s = 0; s < 4; s++) {
      short8 b0 = *reinterpret_cast<const short8*>(sB + ((t0 * 4 + s) * 64 + lane) * 8);
      short8 b1 = *reinterpret_cast<const short8*>(sB + ((t1 * 4 + s) * 64 + lane) * 8);
      aa = __builtin_amdgcn_mfma_f32_16x16x32_bf16(a3[s], b0, aa, 0, 0, 0);
      ab = __builtin_amdgcn_mfma_f32_16x16x32_bf16(a3[s], b1, ab, 0, 0, 0);
    }
    #pragma unroll
    for (int e = 0; e < 2; e++) {
      const int t = e ? t1 : t0;
      const f32x4 ac = e ? ab : aa;
      int c = 16 * t + l15;
      float g0 = ac[0], g1 = ac[1], g2 = ac[2], g3 = ac[3];
      float mx = fmaxf(fmaxf(g0, g1), fmaxf(g2, g3));
      mx = fmaxf(mx, __shfl_xor(mx, 16));
      mx = fmaxf(mx, __shfl_xor(mx, 32));
      float e0 = __expf(g0 - mx), e1 = __expf(g1 - mx);
      float e2 = __expf(g2 - mx), e3 = __expf(g3 - mx);
      float ls = e0 + e1 + e2 + e3;
      ls += __shfl_xor(ls, 16);
      ls += __shfl_xor(ls, 32);
      float pp = e0 * lo_f(vpe_pk[t][0]) + e1 * hi_f(vpe_pk[t][0])
               + e2 * lo_f(vpe_pk[t][1]) + e3 * hi_f(vpe_pk[t][1]);
      pp += __shfl_xor(pp, 16);
      pp += __shfl_xor(pp, 32);
      if (quad == 0) sagg[w][c] = pp * __builtin_amdgcn_rcpf(ls);
    }
  }
  __syncthreads();   // barrier 6: sagg rows 0-7 complete

  // ---- fused Wo: out = sagg @ Wo + bo (wave w = output tile w) ----
  {
    short8 ah[4], al[4];
    #pragma unroll
    for (int s = 0; s < 4; s++) {
      f32x4 x0 = *reinterpret_cast<const f32x4*>(&sagg[l15][32 * s + quad * 8]);
      f32x4 x1 = *reinterpret_cast<const f32x4*>(&sagg[l15][32 * s + quad * 8 + 4]);
      split_frag(x0, x1, ah[s], al[s]);
    }
    f32x4 aw = {0.f, 0.f, 0.f, 0.f};
    #pragma unroll
    for (int s = 0; s < 4; s++) {
      short8 bh = *reinterpret_cast<const short8*>(fwoh + ((w * 4 + s) * 64 + lane) * 8);
      short8 bl = *reinterpret_cast<const short8*>(fwol + ((w * 4 + s) * 64 + lane) * 8);
      aw = __builtin_amdgcn_mfma_f32_16x16x32_bf16(ah[s], bh, aw, 0, 0, 0);
      aw = __builtin_amdgcn_mfma_f32_16x16x32_bf16(ah[s], bl, aw, 0, 0, 0);
      aw = __builtin_amdgcn_mfma_f32_16x16x32_bf16(al[s], bh, aw, 0, 0, 0);
    }
    int c = 16 * w + l15;
    float bb = bo[c];
    if (quad < 2) {   // rows 0-7 valid (8 nodes/block)
      #pragma unroll
      for (int r = 0; r < 4; r++)
        out[(nb0 + quad * 4 + r) * 128 + c] = aw[r] + bb;
    }
  }
}

extern "C" void kernel_launch(void* const* d_in, const int* in_sizes, int n_in,
                              void* d_out, int out_size, void* d_ws, size_t ws_size,
                              hipStream_t stream) {
  const float* x   = (const float*)d_in[0];
  const float* pos = (const float*)d_in[1];
  const int*   idx = (const int*)d_in[2];
  const float* Wq  = (const float*)d_in[3];
  const float* bq  = (const float*)d_in[4];
  const float* Wkv = (const float*)d_in[5];
  const float* bkv = (const float*)d_in[6];
  const float* Wp1 = (const float*)d_in[7];
  const float* bp1 = (const float*)d_in[8];
  const float* Wp2 = (const float*)d_in[9];
  const float* bp2 = (const float*)d_in[10];
  const float* Wa1 = (const float*)d_in[11];
  const float* ba1 = (const float*)d_in[12];
  const float* Wa2 = (const float*)d_in[13];
  const float* Wo  = (const float*)d_in[15];
  const float* bo  = (const float*)d_in[16];

  char* ws = (char*)d_ws;
  short* fwp2 = (short*)(ws + 98304);
  short* fwa1 = (short*)(ws + 131072);
  short* fwa2 = (short*)(ws + 163840);
  short* fwoh = (short*)(ws + 196608);
  short* fwol = (short*)(ws + 229376);
  float* qb = (float*)(ws + 262144);                               // 8 MB f32
  unsigned short* kb = (unsigned short*)(ws + 262144 + 8388608);   // 4 MB bf16
  unsigned short* vb = kb + NN_TOT * 128;                          // 4 MB bf16

  qkv_prep<<<800, 256, 0, stream>>>(x, bq, bkv, Wq, Wkv, Wp2, Wa1, Wa2, Wo,
                                    fwp2, fwa1, fwa2, fwoh, fwol, qb, kb, vb);
  fused_attn_wo<<<2048, 512, 0, stream>>>(pos, idx, Wp1, bp1, bp2, ba1,
                                          fwp2, fwa1, fwa2, fwoh, fwol, bo,
                                          qb, kb, vb, (float*)d_out);
}